// Round 14
// baseline (123.638 us; speedup 1.0000x reference)
//
#include <hip/hip_runtime.h>
#include <math.h>

#define T_TOK 131072
#define NCODE 512

// output layout (float32, concatenated in return order)
#define OFF_LOSS 0
#define OFF_Q    1                    // 8388608 elements
#define OFF_PERP 8388609
#define OFF_CB   8388610              // 32768 elements
#define OFF_IDX  8421378              // 131072 elements

// ws layout (bytes):
//   0      : float loss_acc
//   8      : int   done_counter (last-block-done)
//   64     : int counts[512]
//   4096   : float cbn[512*64]      normalized codebook fp32
//   135168 : uint4 apack[8cc][4ct][3s][2h][64 lanes]  split bf16 codebook
#define CBN_OFF   4096
#define APACK_OFF 135168

typedef short bf8   __attribute__((ext_vector_type(8)));
typedef float f32x4 __attribute__((ext_vector_type(4)));

__device__ __forceinline__ unsigned short f2bf(float f) {
    unsigned u = __float_as_uint(f);
    return (unsigned short)((u + 0x7FFFu + ((u >> 16) & 1u)) >> 16);   // RNE
}
__device__ __forceinline__ float bf2f(unsigned short h) {
    return __uint_as_float(((unsigned)h) << 16);
}
union PK { unsigned short u[8]; uint4 v; };

// ---- prep: 8 blocks x 64 threads, one code per thread ----
__global__ __launch_bounds__(64) void prep_kernel(const float* __restrict__ cb,
                                                  float* __restrict__ out,
                                                  float* __restrict__ cbn,
                                                  uint4* __restrict__ apack,
                                                  int* __restrict__ counts_g,
                                                  float* __restrict__ loss_g,
                                                  int* __restrict__ done_g)
{
    const int c = blockIdx.x * 64 + threadIdx.x;
    float v[64];
    float s = 0.f;
    const float4* src = (const float4*)(cb + c * 64);
    float4* rawdst = (float4*)(out + OFF_CB + c * 64);
    #pragma unroll
    for (int q = 0; q < 16; ++q) {
        float4 t = src[q];
        v[4*q] = t.x; v[4*q+1] = t.y; v[4*q+2] = t.z; v[4*q+3] = t.w;
        s = fmaf(t.x,t.x, fmaf(t.y,t.y, fmaf(t.z,t.z, fmaf(t.w,t.w, s))));
        rawdst[q] = t;                                  // raw passthrough
    }
    const float inv = 1.0f / fmaxf(sqrtf(s), 1e-12f);
    const int cc = c >> 6, ct = (c >> 4) & 3, cl = c & 15;
    const int base = (cc * 4 + ct) * 3;
    #pragma unroll
    for (int g = 0; g < 8; ++g) {                       // h = g>>2, lg = g&3
        PK ph, pm, pl;
        #pragma unroll
        for (int j = 0; j < 8; ++j) {
            float f = v[g * 8 + j] * inv;
            cbn[c * 64 + g * 8 + j] = f;
            ph.u[j] = f2bf(f);
            float r1 = f - bf2f(ph.u[j]);               // exact Dekker residual
            pm.u[j] = f2bf(r1);
            float r2 = r1 - bf2f(pm.u[j]);              // exact
            pl.u[j] = f2bf(r2);
        }
        const int h = g >> 2, lg = g & 3;
        apack[((base + 0) * 2 + h) * 64 + lg * 16 + cl] = ph.v;
        apack[((base + 1) * 2 + h) * 64 + lg * 16 + cl] = pm.v;
        apack[((base + 2) * 2 + h) * 64 + lg * 16 + cl] = pl.v;
    }
    counts_g[c] = 0;
    if (c == 0) { loss_g[0] = 0.f; done_g[0] = 0; }
}

// one (A-split sA, B-split sb) pass: 8 independent chains issued per half,
// dependent re-use distance = 8. Per-chain order (h=0 then h=1) identical
// to all prior passing rounds -> bit-identical accumulation.
#define PASS(sb, sA)                                                                     \
    {                                                                                    \
        _Pragma("unroll")                                                                \
        for (int tt = 0; tt < 4; ++tt) {                                                 \
            acc0[tt] = __builtin_amdgcn_mfma_f32_16x16x32_bf16(Af[0][sA][0], bfr[sb][0][tt], acc0[tt], 0, 0, 0); \
            acc1[tt] = __builtin_amdgcn_mfma_f32_16x16x32_bf16(Af[1][sA][0], bfr[sb][0][tt], acc1[tt], 0, 0, 0); \
        }                                                                                \
        _Pragma("unroll")                                                                \
        for (int tt = 0; tt < 4; ++tt) {                                                 \
            acc0[tt] = __builtin_amdgcn_mfma_f32_16x16x32_bf16(Af[0][sA][1], bfr[sb][1][tt], acc0[tt], 0, 0, 0); \
            acc1[tt] = __builtin_amdgcn_mfma_f32_16x16x32_bf16(Af[1][sA][1], bfr[sb][1][tt], acc1[tt], 0, 0, 0); \
        }                                                                                \
    }

// issue order s = 2,1,0: pass `lh` consumes s=2 first, so first-needed loads
// are oldest in the vm queue -> compiler can start MFMAs at partial vmcnt.
#define LOADAF(cc, ct0)                                                                  \
    {                                                                                    \
        _Pragma("unroll")                                                                \
        for (int s_ = 2; s_ >= 0; --s_)                                                  \
            _Pragma("unroll")                                                            \
            for (int c_ = 0; c_ < 2; ++c_)                                               \
                _Pragma("unroll")                                                        \
                for (int h_ = 0; h_ < 2; ++h_)                                           \
                    Af[c_][s_][h_] = ag[(((((cc) * 4 + (ct0) + c_) * 3) + s_) * 2 + h_) * 64 + lane]; \
    }

// pass order small->large: lh, mm, mh, hl, hm, hh
#define SIXPASS PASS(0, 2) PASS(1, 1) PASS(0, 1) PASS(2, 0) PASS(1, 0) PASS(0, 0)

__global__ __launch_bounds__(256, 2) void main_kernel(const float* __restrict__ x,
                                                      const float* __restrict__ cbn,
                                                      const uint4* __restrict__ apack,
                                                      int* __restrict__ counts_g,
                                                      float* __restrict__ loss_g,
                                                      int* __restrict__ done_g,
                                                      float* __restrict__ out)
{
    __shared__ int counts_lds[NCODE];
    __shared__ double dred[256];
    __shared__ int islast;

    const int tid  = threadIdx.x;
    const int lane = tid & 63;
    const int wv   = tid >> 6;                          // 0..3
    const int lx   = lane & 15;
    const int lg   = lane >> 4;
    const int tok0 = blockIdx.x * 256;                  // 256 tokens per block
    const int wt   = wv * 64;                           // 64 tokens per wave

    counts_lds[tid] = 0; counts_lds[tid + 256] = 0;

    // ---- load + split own token fragments directly from global (no LDS for B) ----
    // lane owns tokens wt + tt*16 + lx (tt=0..3), dims lg*8..+8 and 32+lg*8..+8
    bf8 bfr[3][2][4];                                   // [split][h][tt] = 96 regs
    float inv_n[4];
    #pragma unroll
    for (int tt = 0; tt < 4; ++tt) {
        float ss = 0.f;
        const float* xr = x + (size_t)(tok0 + wt + tt * 16 + lx) * 64 + lg * 8;
        #pragma unroll
        for (int h = 0; h < 2; ++h) {
            float4 a = *(const float4*)(xr + h * 32);
            float4 b = *(const float4*)(xr + h * 32 + 4);
            float f[8] = {a.x, a.y, a.z, a.w, b.x, b.y, b.z, b.w};
            PK ph, pm, pl;
            #pragma unroll
            for (int j = 0; j < 8; ++j) {
                ss = fmaf(f[j], f[j], ss);
                ph.u[j] = f2bf(f[j]);
                float r1 = f[j] - bf2f(ph.u[j]);
                pm.u[j] = f2bf(r1);
                float r2 = r1 - bf2f(pm.u[j]);
                pl.u[j] = f2bf(r2);
            }
            bfr[0][h][tt] = *(bf8*)&ph;
            bfr[1][h][tt] = *(bf8*)&pm;
            bfr[2][h][tt] = *(bf8*)&pl;
        }
        // full |x|^2: reduce over the 4 lg-groups sharing this token column
        ss += __shfl_xor(ss, 16);
        ss += __shfl_xor(ss, 32);
        inv_n[tt] = 1.0f / fmaxf(sqrtf(ss), 1e-12f);
    }
    // no barrier here: waves enter the loop staggered (phase diversity for
    // setprio). counts_lds-zeroing barrier is just before the atomics.

    float bm[4] = {-3e38f, -3e38f, -3e38f, -3e38f};
    int   bi[4] = {0, 0, 0, 0};

    const bf8* ag = (const bf8*)apack;                  // L1/L2-resident (196 KB total)

    #pragma unroll 1
    for (int ph = 0; ph < 16; ++ph) {
        const int cc = ph >> 1, ct0 = (ph & 1) * 2;
        bf8 Af[2][3][2];                                // [ct][s][h] = 48 regs
        LOADAF(cc, ct0)

        f32x4 zero = {0.f, 0.f, 0.f, 0.f};
        f32x4 acc0[4] = {zero, zero, zero, zero};
        f32x4 acc1[4] = {zero, zero, zero, zero};

        __builtin_amdgcn_s_setprio(1);                  // T5: favor MFMA-holding wave
        SIXPASS
        __builtin_amdgcn_s_setprio(0);

        // running argmax, strictly ascending code order (first-max tie rule)
        const int cb0 = cc * 64 + ct0 * 16 + lg * 4;
        #pragma unroll
        for (int tt = 0; tt < 4; ++tt)
            #pragma unroll
            for (int j = 0; j < 4; ++j)
                if (acc0[tt][j] > bm[tt]) { bm[tt] = acc0[tt][j]; bi[tt] = cb0 + j; }
        #pragma unroll
        for (int tt = 0; tt < 4; ++tt)
            #pragma unroll
            for (int j = 0; j < 4; ++j)
                if (acc1[tt][j] > bm[tt]) { bm[tt] = acc1[tt][j]; bi[tt] = cb0 + 16 + j; }
    }

    // ---- combine lanes {l, l^16, l^32, l^48} (same token column), min-index ties ----
    #pragma unroll
    for (int tt = 0; tt < 4; ++tt) {
        #pragma unroll
        for (int off = 16; off < 64; off <<= 1) {
            float v2 = __shfl_xor(bm[tt], off);
            int   i2 = __shfl_xor(bi[tt], off);
            if (v2 > bm[tt] || (v2 == bm[tt] && i2 < bi[tt])) { bm[tt] = v2; bi[tt] = i2; }
        }
    }

    __syncthreads();                                    // counts zeroed before atomics

    if (lg == 0) {                                      // lanes 0-15: one per token column
        float lp = 0.f;
        #pragma unroll
        for (int tt = 0; tt < 4; ++tt) {
            atomicAdd(&counts_lds[bi[tt]], 1);
            out[OFF_IDX + tok0 + wt + tt * 16 + lx] = (float)bi[tt];
            // ||q - x_hat||^2 = 2 - 2*cos ; cos = (x . c_hat) * inv|x|
            lp += 2.f - 2.f * bm[tt] * inv_n[tt];
        }
        lp += __shfl_xor(lp, 1); lp += __shfl_xor(lp, 2);
        lp += __shfl_xor(lp, 4); lp += __shfl_xor(lp, 8);
        if (lx == 0) atomicAdd(loss_g, lp);
    }

    // ---- quantized_st rows: idx broadcast by shfl, row gather from L2-resident cbn ----
    #pragma unroll
    for (int tt = 0; tt < 4; ++tt) {
        const int b = bi[tt];
        #pragma unroll 4
        for (int i = 0; i < 16; ++i) {
            int idx = __shfl(b, i);
            out[OFF_Q + (size_t)(tok0 + wt + tt * 16 + i) * 64 + lane] = cbn[idx * 64 + lane];
        }
    }

    __syncthreads();                                    // all histogram atomics done
    int c0 = counts_lds[tid], c1 = counts_lds[tid + 256];
    if (c0) atomicAdd(&counts_g[tid], c0);
    if (c1) atomicAdd(&counts_g[tid + 256], c1);

    // ---- last-block-done: the 512th block to finish computes loss & perplexity ----
    __threadfence();                                    // publish counts/loss writes
    if (tid == 0) islast = (atomicAdd(done_g, 1) == (int)gridDim.x - 1) ? 1 : 0;
    __syncthreads();
    if (islast) {
        __threadfence();                                // acquire all blocks' writes
        // summation tree bit-identical to the old fin_kernel (512 threads):
        // step s=256 there produced red[t] = f(t) + f(t+256); replicate directly.
        const float p0 = (float)counts_g[tid]       * (1.0f / (float)T_TOK);
        const float p1 = (float)counts_g[tid + 256] * (1.0f / (float)T_TOK);
        dred[tid] = (double)(p0 * logf(p0 + 1e-10f)) + (double)(p1 * logf(p1 + 1e-10f));
        __syncthreads();
        for (int s = 128; s > 0; s >>= 1) {
            if (tid < s) dred[tid] += dred[tid + s];
            __syncthreads();
        }
        if (tid == 0) {
            out[OFF_PERP] = expf(-(float)dred[0]);
            out[OFF_LOSS] = loss_g[0] * (1.25f / ((float)T_TOK * 64.f));
        }
    }
}

extern "C" void kernel_launch(void* const* d_in, const int* in_sizes, int n_in,
                              void* d_out, int out_size, void* d_ws, size_t ws_size,
                              hipStream_t stream)
{
    const float* x  = (const float*)d_in[0];   // [128,8,128,64] fp32
    const float* cb = (const float*)d_in[1];   // [512,64] fp32
    float* out = (float*)d_out;
    char*  ws  = (char*)d_ws;
    float* loss_g   = (float*)(ws);
    int*   done_g   = (int*)(ws + 8);
    int*   counts_g = (int*)(ws + 64);
    float* cbn      = (float*)(ws + CBN_OFF);
    uint4* apack    = (uint4*)(ws + APACK_OFF);

    prep_kernel<<<8, 64, 0, stream>>>(cb, out, cbn, apack, counts_g, loss_g, done_g);
    main_kernel<<<T_TOK / 256, 256, 0, stream>>>(x, cbn, apack, counts_g, loss_g, done_g, out);
}

// Round 15
// 71.922 us; speedup vs baseline: 1.7191x; 1.7191x over previous
//
#include <hip/hip_runtime.h>
#include <math.h>

#define T_TOK 131072
#define NCODE 512

// output layout (float32, concatenated in return order)
#define OFF_LOSS 0
#define OFF_Q    1                    // 8388608 elements
#define OFF_PERP 8388609
#define OFF_CB   8388610              // 32768 elements
#define OFF_IDX  8421378              // 131072 elements

// ws layout (bytes):
//   0      : float loss_acc
//   64     : int counts[512]
//   4096   : float cbn[512*64]      normalized codebook fp32
//   135168 : uint4 apack[8cc][4ct][3s][2h][64 lanes]  split bf16 codebook
#define CBN_OFF   4096
#define APACK_OFF 135168

typedef short bf8   __attribute__((ext_vector_type(8)));
typedef float f32x4 __attribute__((ext_vector_type(4)));

__device__ __forceinline__ unsigned short f2bf(float f) {
    unsigned u = __float_as_uint(f);
    return (unsigned short)((u + 0x7FFFu + ((u >> 16) & 1u)) >> 16);   // RNE
}
__device__ __forceinline__ float bf2f(unsigned short h) {
    return __uint_as_float(((unsigned)h) << 16);
}
union PK { unsigned short u[8]; uint4 v; };

// ---- prep: 8 blocks x 64 threads, one code per thread ----
__global__ __launch_bounds__(64) void prep_kernel(const float* __restrict__ cb,
                                                  float* __restrict__ out,
                                                  float* __restrict__ cbn,
                                                  uint4* __restrict__ apack,
                                                  int* __restrict__ counts_g,
                                                  float* __restrict__ loss_g)
{
    const int c = blockIdx.x * 64 + threadIdx.x;
    float v[64];
    float s = 0.f;
    const float4* src = (const float4*)(cb + c * 64);
    float4* rawdst = (float4*)(out + OFF_CB + c * 64);
    #pragma unroll
    for (int q = 0; q < 16; ++q) {
        float4 t = src[q];
        v[4*q] = t.x; v[4*q+1] = t.y; v[4*q+2] = t.z; v[4*q+3] = t.w;
        s = fmaf(t.x,t.x, fmaf(t.y,t.y, fmaf(t.z,t.z, fmaf(t.w,t.w, s))));
        rawdst[q] = t;                                  // raw passthrough
    }
    const float inv = 1.0f / fmaxf(sqrtf(s), 1e-12f);
    const int cc = c >> 6, ct = (c >> 4) & 3, cl = c & 15;
    const int base = (cc * 4 + ct) * 3;
    #pragma unroll
    for (int g = 0; g < 8; ++g) {                       // h = g>>2, lg = g&3
        PK ph, pm, pl;
        #pragma unroll
        for (int j = 0; j < 8; ++j) {
            float f = v[g * 8 + j] * inv;
            cbn[c * 64 + g * 8 + j] = f;
            ph.u[j] = f2bf(f);
            float r1 = f - bf2f(ph.u[j]);               // exact Dekker residual
            pm.u[j] = f2bf(r1);
            float r2 = r1 - bf2f(pm.u[j]);              // exact
            pl.u[j] = f2bf(r2);
        }
        const int h = g >> 2, lg = g & 3;
        apack[((base + 0) * 2 + h) * 64 + lg * 16 + cl] = ph.v;
        apack[((base + 1) * 2 + h) * 64 + lg * 16 + cl] = pm.v;
        apack[((base + 2) * 2 + h) * 64 + lg * 16 + cl] = pl.v;
    }
    counts_g[c] = 0;
    if (c == 0) loss_g[0] = 0.f;
}

// one (A-split sA, B-split sb) pass: 8 independent chains issued per half,
// dependent re-use distance = 8. Per-chain order (h=0 then h=1) identical
// to all prior passing rounds -> bit-identical accumulation.
#define PASS(sb, sA)                                                                     \
    {                                                                                    \
        _Pragma("unroll")                                                                \
        for (int tt = 0; tt < 4; ++tt) {                                                 \
            acc0[tt] = __builtin_amdgcn_mfma_f32_16x16x32_bf16(Af[0][sA][0], bfr[sb][0][tt], acc0[tt], 0, 0, 0); \
            acc1[tt] = __builtin_amdgcn_mfma_f32_16x16x32_bf16(Af[1][sA][0], bfr[sb][0][tt], acc1[tt], 0, 0, 0); \
        }                                                                                \
        _Pragma("unroll")                                                                \
        for (int tt = 0; tt < 4; ++tt) {                                                 \
            acc0[tt] = __builtin_amdgcn_mfma_f32_16x16x32_bf16(Af[0][sA][1], bfr[sb][1][tt], acc0[tt], 0, 0, 0); \
            acc1[tt] = __builtin_amdgcn_mfma_f32_16x16x32_bf16(Af[1][sA][1], bfr[sb][1][tt], acc1[tt], 0, 0, 0); \
        }                                                                                \
    }

// issue order s = 2,1,0: pass `lh` consumes s=2 first, so first-needed loads
// are oldest in the vm queue -> compiler can start MFMAs at partial vmcnt.
#define LOADAF(cc, ct0)                                                                  \
    {                                                                                    \
        _Pragma("unroll")                                                                \
        for (int s_ = 2; s_ >= 0; --s_)                                                  \
            _Pragma("unroll")                                                            \
            for (int c_ = 0; c_ < 2; ++c_)                                               \
                _Pragma("unroll")                                                        \
                for (int h_ = 0; h_ < 2; ++h_)                                           \
                    Af[c_][s_][h_] = ag[(((((cc) * 4 + (ct0) + c_) * 3) + s_) * 2 + h_) * 64 + lane]; \
    }

// pass order small->large: lh, mm, mh, hl, hm, hh
#define SIXPASS PASS(0, 2) PASS(1, 1) PASS(0, 1) PASS(2, 0) PASS(1, 0) PASS(0, 0)

__global__ __launch_bounds__(256, 2) void main_kernel(const float* __restrict__ x,
                                                      const float* __restrict__ cbn,
                                                      const uint4* __restrict__ apack,
                                                      int* __restrict__ counts_g,
                                                      float* __restrict__ loss_g,
                                                      float* __restrict__ out)
{
    __shared__ int counts_lds[NCODE];                   // only LDS in the kernel

    const int tid  = threadIdx.x;
    const int lane = tid & 63;
    const int wv   = tid >> 6;                          // 0..3
    const int lx   = lane & 15;
    const int lg   = lane >> 4;
    const int tok0 = blockIdx.x * 256;                  // 256 tokens per block
    const int wt   = wv * 64;                           // 64 tokens per wave

    counts_lds[tid] = 0; counts_lds[tid + 256] = 0;

    // ---- load + split own token fragments directly from global (no LDS for B) ----
    // lane owns tokens wt + tt*16 + lx (tt=0..3), dims lg*8..+8 and 32+lg*8..+8
    bf8 bfr[3][2][4];                                   // [split][h][tt] = 96 regs
    float inv_n[4];
    #pragma unroll
    for (int tt = 0; tt < 4; ++tt) {
        float ss = 0.f;
        const float* xr = x + (size_t)(tok0 + wt + tt * 16 + lx) * 64 + lg * 8;
        #pragma unroll
        for (int h = 0; h < 2; ++h) {
            float4 a = *(const float4*)(xr + h * 32);
            float4 b = *(const float4*)(xr + h * 32 + 4);
            float f[8] = {a.x, a.y, a.z, a.w, b.x, b.y, b.z, b.w};
            PK ph, pm, pl;
            #pragma unroll
            for (int j = 0; j < 8; ++j) {
                ss = fmaf(f[j], f[j], ss);
                ph.u[j] = f2bf(f[j]);
                float r1 = f[j] - bf2f(ph.u[j]);
                pm.u[j] = f2bf(r1);
                float r2 = r1 - bf2f(pm.u[j]);
                pl.u[j] = f2bf(r2);
            }
            bfr[0][h][tt] = *(bf8*)&ph;
            bfr[1][h][tt] = *(bf8*)&pm;
            bfr[2][h][tt] = *(bf8*)&pl;
        }
        // full |x|^2: reduce over the 4 lg-groups sharing this token column
        ss += __shfl_xor(ss, 16);
        ss += __shfl_xor(ss, 32);
        inv_n[tt] = 1.0f / fmaxf(sqrtf(ss), 1e-12f);
    }
    // no barrier here: waves enter the loop staggered (phase diversity for
    // setprio). counts_lds-zeroing barrier is just before the atomics.

    float bm[4] = {-3e38f, -3e38f, -3e38f, -3e38f};
    int   bi[4] = {0, 0, 0, 0};

    const bf8* ag = (const bf8*)apack;                  // L1/L2-resident (196 KB total)

    // Software-pipelined single-buffer: LOADAF(ph+1) issues right after the
    // last MFMA consuming Af(ph) (WAR safe: in-order issue), so the loads fly
    // under the argmax + loop-back instead of stalling the next phase's start.
    bf8 Af[2][3][2];                                    // [ct][s][h] = 48 regs
    LOADAF(0, 0)                                        // prologue: phase 0

    #pragma unroll 1
    for (int ph = 0; ph < 16; ++ph) {
        const int cc = ph >> 1, ct0 = (ph & 1) * 2;

        f32x4 zero = {0.f, 0.f, 0.f, 0.f};
        f32x4 acc0[4] = {zero, zero, zero, zero};
        f32x4 acc1[4] = {zero, zero, zero, zero};

        __builtin_amdgcn_s_setprio(1);                  // T5: favor MFMA-holding wave
        SIXPASS
        __builtin_amdgcn_s_setprio(0);

        if (ph < 15) {                                  // prefetch next phase's A frags
            const int ncc = (ph + 1) >> 1, nct0 = ((ph + 1) & 1) * 2;
            LOADAF(ncc, nct0)
        }

        // running argmax, strictly ascending code order (first-max tie rule)
        const int cb0 = cc * 64 + ct0 * 16 + lg * 4;
        #pragma unroll
        for (int tt = 0; tt < 4; ++tt)
            #pragma unroll
            for (int j = 0; j < 4; ++j)
                if (acc0[tt][j] > bm[tt]) { bm[tt] = acc0[tt][j]; bi[tt] = cb0 + j; }
        #pragma unroll
        for (int tt = 0; tt < 4; ++tt)
            #pragma unroll
            for (int j = 0; j < 4; ++j)
                if (acc1[tt][j] > bm[tt]) { bm[tt] = acc1[tt][j]; bi[tt] = cb0 + 16 + j; }
    }

    // ---- combine lanes {l, l^16, l^32, l^48} (same token column), min-index ties ----
    #pragma unroll
    for (int tt = 0; tt < 4; ++tt) {
        #pragma unroll
        for (int off = 16; off < 64; off <<= 1) {
            float v2 = __shfl_xor(bm[tt], off);
            int   i2 = __shfl_xor(bi[tt], off);
            if (v2 > bm[tt] || (v2 == bm[tt] && i2 < bi[tt])) { bm[tt] = v2; bi[tt] = i2; }
        }
    }

    __syncthreads();                                    // counts zeroed before atomics

    if (lg == 0) {                                      // lanes 0-15: one per token column
        float lp = 0.f;
        #pragma unroll
        for (int tt = 0; tt < 4; ++tt) {
            atomicAdd(&counts_lds[bi[tt]], 1);
            out[OFF_IDX + tok0 + wt + tt * 16 + lx] = (float)bi[tt];
            // ||q - x_hat||^2 = 2 - 2*cos ; cos = (x . c_hat) * inv|x|
            lp += 2.f - 2.f * bm[tt] * inv_n[tt];
        }
        lp += __shfl_xor(lp, 1); lp += __shfl_xor(lp, 2);
        lp += __shfl_xor(lp, 4); lp += __shfl_xor(lp, 8);
        if (lx == 0) atomicAdd(loss_g, lp);
    }

    // ---- quantized_st rows: idx broadcast by shfl, row gather from L2-resident cbn ----
    #pragma unroll
    for (int tt = 0; tt < 4; ++tt) {
        const int b = bi[tt];
        #pragma unroll 4
        for (int i = 0; i < 16; ++i) {
            int idx = __shfl(b, i);
            out[OFF_Q + (size_t)(tok0 + wt + tt * 16 + i) * 64 + lane] = cbn[idx * 64 + lane];
        }
    }

    __syncthreads();                                    // all histogram atomics done
    int c0 = counts_lds[tid], c1 = counts_lds[tid + 256];
    if (c0) atomicAdd(&counts_g[tid], c0);
    if (c1) atomicAdd(&counts_g[tid + 256], c1);
}

__global__ __launch_bounds__(512) void fin_kernel(const int* __restrict__ counts_g,
                                                  const float* __restrict__ loss_g,
                                                  float* __restrict__ out)
{
    __shared__ double red[512];
    int t = threadIdx.x;
    float p = (float)counts_g[t] * (1.0f / (float)T_TOK);
    red[t] = (double)(p * logf(p + 1e-10f));
    __syncthreads();
    for (int s = 256; s > 0; s >>= 1) {
        if (t < s) red[t] += red[t + s];
        __syncthreads();
    }
    if (t == 0) {
        out[OFF_PERP] = expf(-(float)red[0]);
        out[OFF_LOSS] = loss_g[0] * (1.25f / ((float)T_TOK * 64.f));
    }
}

extern "C" void kernel_launch(void* const* d_in, const int* in_sizes, int n_in,
                              void* d_out, int out_size, void* d_ws, size_t ws_size,
                              hipStream_t stream)
{
    const float* x  = (const float*)d_in[0];   // [128,8,128,64] fp32
    const float* cb = (const float*)d_in[1];   // [512,64] fp32
    float* out = (float*)d_out;
    char*  ws  = (char*)d_ws;
    float* loss_g   = (float*)(ws);
    int*   counts_g = (int*)(ws + 64);
    float* cbn      = (float*)(ws + CBN_OFF);
    uint4* apack    = (uint4*)(ws + APACK_OFF);

    prep_kernel<<<8, 64, 0, stream>>>(cb, out, cbn, apack, counts_g, loss_g);
    main_kernel<<<T_TOK / 256, 256, 0, stream>>>(x, cbn, apack, counts_g, loss_g, out);
    fin_kernel<<<1, 512, 0, stream>>>(counts_g, loss_g, out);
}